// Round 3
// baseline (1047.671 us; speedup 1.0000x reference)
//
#include <hip/hip_runtime.h>
#include <math.h>

#define N_NODES 100000
#define N_EDGES 1600000
#define DIN 128
#define DH 64
#define DOUT 40

#define NB 256      // dst buckets
#define BN 391      // nodes per bucket (256*391 = 100096 >= 100000)
#define CAP 8192    // staged capacity per bucket (mean 6250, sigma ~79)
#define EPB 6250    // edges per k_bin block

typedef unsigned short u16;
typedef unsigned int u32;

__device__ inline float bf2f(u16 u) {
    return __uint_as_float(((u32)u) << 16);
}
__device__ inline u16 f2bf(float f) {
    u32 u = __float_as_uint(f);
    u32 r = (u + 0x7FFFu + ((u >> 16) & 1u)) >> 16;  // RNE
    return (u16)r;
}

// ---------------- pass A: bin edges by dst bucket ----------------
// staged entry: src (17 bits) | dstlocal (9 bits) << 17

__global__ __launch_bounds__(256) void k_bin(const int* __restrict__ src,
                                             const int* __restrict__ dst,
                                             int* __restrict__ gcur,
                                             u32* __restrict__ staged) {
    __shared__ int hist[NB];
    __shared__ int base[NB];
    __shared__ int cur[NB];
    int t = threadIdx.x;
    for (int i = t; i < NB; i += 256) { hist[i] = 0; cur[i] = 0; }
    __syncthreads();
    int e0 = blockIdx.x * EPB;
    int e1 = e0 + EPB; if (e1 > N_EDGES) e1 = N_EDGES;
    for (int e = e0 + t; e < e1; e += 256)
        atomicAdd(&hist[dst[e] / BN], 1);
    __syncthreads();
    for (int i = t; i < NB; i += 256) {
        int h = hist[i];
        base[i] = h ? atomicAdd(&gcur[i], h) : 0;
    }
    __syncthreads();
    for (int e = e0 + t; e < e1; e += 256) {
        int d = dst[e], s = src[e];
        int b = d / BN;
        int dl = d - b * BN;
        int r = base[b] + atomicAdd(&cur[b], 1);
        if (r < CAP) staged[(size_t)b * CAP + r] = (u32)s | ((u32)dl << 17);
    }
}

// ---------------- dinv from staged (deg = in-degree by dst) ----------------

__global__ __launch_bounds__(256) void k_dinv(const int* __restrict__ gcur,
                                              const u32* __restrict__ staged,
                                              float* __restrict__ dinv) {
    __shared__ int hist[BN];
    int b = blockIdx.x, t = threadIdx.x;
    for (int i = t; i < BN; i += 256) hist[i] = 0;
    __syncthreads();
    int cnt = gcur[b]; if (cnt > CAP) cnt = CAP;
    const u32* sb = staged + (size_t)b * CAP;
    for (int i = t; i < cnt; i += 256) atomicAdd(&hist[sb[i] >> 17], 1);
    __syncthreads();
    int n0 = b * BN;
    for (int i = t; i < BN; i += 256) {
        int n = n0 + i;
        if (n < N_NODES) dinv[n] = rsqrtf((float)hist[i] + 1.0f);
    }
}

// ---------------- GEMM1: h1s = bf16((x @ W1) * dinv[row])  [N,64] ----------------

__global__ __launch_bounds__(256) void k_gemm1(const float* __restrict__ x,
                                               const float* __restrict__ W1,
                                               const float* __restrict__ dinv,
                                               u16* __restrict__ h1s) {
    __shared__ float xs[64 * 132];
    __shared__ float wsh[DIN * DH];
    int t = threadIdx.x;
    int row0 = blockIdx.x * 64;

    for (int it = 0; it < 8; ++it) {
        int idx = (it * 256 + t) * 4;
        int r = idx >> 7, c = idx & 127;
        float4 v = make_float4(0.f, 0.f, 0.f, 0.f);
        if (row0 + r < N_NODES) v = *(const float4*)&x[(size_t)(row0 + r) * DIN + c];
        *(float4*)&xs[r * 132 + c] = v;
    }
    for (int it = 0; it < 8; ++it) {
        int idx = (it * 256 + t) * 4;
        *(float4*)&wsh[idx] = *(const float4*)&W1[idx];
    }
    __syncthreads();

    int tr = t & 15;
    int tc = t >> 4;
    float acc[4][4] = {};
    for (int k = 0; k < DIN; ++k) {
        float4 wv = *(const float4*)&wsh[k * DH + tr * 4];
#pragma unroll
        for (int i = 0; i < 4; ++i) {
            float xv = xs[(tc * 4 + i) * 132 + k];
            acc[i][0] += xv * wv.x;
            acc[i][1] += xv * wv.y;
            acc[i][2] += xv * wv.z;
            acc[i][3] += xv * wv.w;
        }
    }
#pragma unroll
    for (int i = 0; i < 4; ++i) {
        int row = row0 + tc * 4 + i;
        if (row < N_NODES) {
            float dv = dinv[row];
            ushort4 o;
            o.x = f2bf(acc[i][0] * dv);
            o.y = f2bf(acc[i][1] * dv);
            o.z = f2bf(acc[i][2] * dv);
            o.w = f2bf(acc[i][3] * dv);
            *(ushort4*)&h1s[(size_t)row * DH + tr * 4] = o;
        }
    }
}

// ---------------- agg1 (push): LDS f32 acc per bucket ----------------
// h1 = relu(dinv[n]*(sum_src h1s[src] + h1s[n]) + b1)

__global__ __launch_bounds__(1024) void k_agg1(const u16* __restrict__ h1s,
                                               const int* __restrict__ gcur,
                                               const u32* __restrict__ staged,
                                               const float* __restrict__ dinv,
                                               const float* __restrict__ b1,
                                               float* __restrict__ h1) {
    __shared__ float acc[BN * 64];  // 100 KB
    int b = blockIdx.x, t = threadIdx.x;
    int n0 = b * BN;
    int nr = N_NODES - n0; if (nr > BN) nr = BN;

    for (int i = t; i < nr * 64; i += 1024) {
        int r = i >> 6, c = i & 63;
        acc[i] = bf2f(h1s[(size_t)(n0 + r) * 64 + c]);  // self-loop term
    }
    __syncthreads();

    int cnt = gcur[b]; if (cnt > CAP) cnt = CAP;
    int lane = t & 63, wave = t >> 6;
    int per = (cnt + 15) >> 4;
    int ws = wave * per;
    int we = ws + per; if (we > cnt) we = cnt;
    const u32* sb = staged + (size_t)b * CAP;

    for (int eb = ws; eb < we; eb += 64) {
        int nn = we - eb; if (nn > 64) nn = 64;
        u32 pk = (lane < nn) ? sb[eb + lane] : 0u;
        int g = 0;
        for (; g + 8 <= nn; g += 8) {
            u32 p0 = __shfl(pk, g + 0, 64); u32 p1 = __shfl(pk, g + 1, 64);
            u32 p2 = __shfl(pk, g + 2, 64); u32 p3 = __shfl(pk, g + 3, 64);
            u32 p4 = __shfl(pk, g + 4, 64); u32 p5 = __shfl(pk, g + 5, 64);
            u32 p6 = __shfl(pk, g + 6, 64); u32 p7 = __shfl(pk, g + 7, 64);
            float v0 = bf2f(h1s[(size_t)(p0 & 0x1FFFF) * 64 + lane]);
            float v1 = bf2f(h1s[(size_t)(p1 & 0x1FFFF) * 64 + lane]);
            float v2 = bf2f(h1s[(size_t)(p2 & 0x1FFFF) * 64 + lane]);
            float v3 = bf2f(h1s[(size_t)(p3 & 0x1FFFF) * 64 + lane]);
            float v4 = bf2f(h1s[(size_t)(p4 & 0x1FFFF) * 64 + lane]);
            float v5 = bf2f(h1s[(size_t)(p5 & 0x1FFFF) * 64 + lane]);
            float v6 = bf2f(h1s[(size_t)(p6 & 0x1FFFF) * 64 + lane]);
            float v7 = bf2f(h1s[(size_t)(p7 & 0x1FFFF) * 64 + lane]);
            atomicAdd(&acc[(p0 >> 17) * 64 + lane], v0);
            atomicAdd(&acc[(p1 >> 17) * 64 + lane], v1);
            atomicAdd(&acc[(p2 >> 17) * 64 + lane], v2);
            atomicAdd(&acc[(p3 >> 17) * 64 + lane], v3);
            atomicAdd(&acc[(p4 >> 17) * 64 + lane], v4);
            atomicAdd(&acc[(p5 >> 17) * 64 + lane], v5);
            atomicAdd(&acc[(p6 >> 17) * 64 + lane], v6);
            atomicAdd(&acc[(p7 >> 17) * 64 + lane], v7);
        }
        for (; g < nn; ++g) {
            u32 p = __shfl(pk, g, 64);
            atomicAdd(&acc[(p >> 17) * 64 + lane],
                      bf2f(h1s[(size_t)(p & 0x1FFFF) * 64 + lane]));
        }
    }
    __syncthreads();

    for (int i = t; i < nr * 64; i += 1024) {
        int r = i >> 6, c = i & 63;
        int n = n0 + r;
        h1[(size_t)n * 64 + c] = fmaxf(acc[i] * dinv[n] + b1[c], 0.f);
    }
}

// ---------------- GEMM2: h2s = bf16((h1 @ W2) * dinv[row])  [N,64-padded] ----------------

__global__ __launch_bounds__(256) void k_gemm2(const float* __restrict__ h1,
                                               const float* __restrict__ W2,
                                               const float* __restrict__ dinv,
                                               u16* __restrict__ h2s) {
    __shared__ float xs[64 * 68];
    __shared__ float wsh[DH * DOUT];
    int t = threadIdx.x;
    int row0 = blockIdx.x * 64;

    for (int it = 0; it < 4; ++it) {
        int idx = (it * 256 + t) * 4;
        int r = idx >> 6, c = idx & 63;
        float4 v = make_float4(0.f, 0.f, 0.f, 0.f);
        if (row0 + r < N_NODES) v = *(const float4*)&h1[(size_t)(row0 + r) * DH + c];
        *(float4*)&xs[r * 68 + c] = v;
    }
    for (int idx = t * 4; idx < DH * DOUT; idx += 1024) {
        *(float4*)&wsh[idx] = *(const float4*)&W2[idx];
    }
    __syncthreads();

    int fg = t & 7;
    int rg = t >> 3;
    float acc[2][5] = {};
    for (int k = 0; k < DH; ++k) {
        float x0 = xs[(rg * 2 + 0) * 68 + k];
        float x1 = xs[(rg * 2 + 1) * 68 + k];
#pragma unroll
        for (int j = 0; j < 5; ++j) {
            float w = wsh[k * DOUT + fg * 5 + j];
            acc[0][j] += x0 * w;
            acc[1][j] += x1 * w;
        }
    }
#pragma unroll
    for (int i = 0; i < 2; ++i) {
        int row = row0 + rg * 2 + i;
        if (row < N_NODES) {
            float dv = dinv[row];
#pragma unroll
            for (int j = 0; j < 5; ++j)
                h2s[(size_t)row * 64 + fg * 5 + j] = f2bf(acc[i][j] * dv);
        }
    }
}

// ---------------- agg2 (push) + bias + log_softmax ----------------

__global__ __launch_bounds__(1024) void k_agg2(const u16* __restrict__ h2s,
                                               const int* __restrict__ gcur,
                                               const u32* __restrict__ staged,
                                               const float* __restrict__ dinv,
                                               const float* __restrict__ b2,
                                               float* __restrict__ out) {
    __shared__ float acc[BN * 40];  // 62.6 KB
    int b = blockIdx.x, t = threadIdx.x;
    int n0 = b * BN;
    int nr = N_NODES - n0; if (nr > BN) nr = BN;

    for (int i = t; i < nr * 40; i += 1024) {
        int r = i / 40, c = i - r * 40;
        acc[i] = bf2f(h2s[(size_t)(n0 + r) * 64 + c]);  // self-loop term
    }
    __syncthreads();

    int cnt = gcur[b]; if (cnt > CAP) cnt = CAP;
    int lane = t & 63, wave = t >> 6;
    bool act = lane < DOUT;
    int per = (cnt + 15) >> 4;
    int ws = wave * per;
    int we = ws + per; if (we > cnt) we = cnt;
    const u32* sb = staged + (size_t)b * CAP;

    for (int eb = ws; eb < we; eb += 64) {
        int nn = we - eb; if (nn > 64) nn = 64;
        u32 pk = (lane < nn) ? sb[eb + lane] : 0u;
        int g = 0;
        for (; g + 8 <= nn; g += 8) {
            u32 p0 = __shfl(pk, g + 0, 64); u32 p1 = __shfl(pk, g + 1, 64);
            u32 p2 = __shfl(pk, g + 2, 64); u32 p3 = __shfl(pk, g + 3, 64);
            u32 p4 = __shfl(pk, g + 4, 64); u32 p5 = __shfl(pk, g + 5, 64);
            u32 p6 = __shfl(pk, g + 6, 64); u32 p7 = __shfl(pk, g + 7, 64);
            if (act) {
                float v0 = bf2f(h2s[(size_t)(p0 & 0x1FFFF) * 64 + lane]);
                float v1 = bf2f(h2s[(size_t)(p1 & 0x1FFFF) * 64 + lane]);
                float v2 = bf2f(h2s[(size_t)(p2 & 0x1FFFF) * 64 + lane]);
                float v3 = bf2f(h2s[(size_t)(p3 & 0x1FFFF) * 64 + lane]);
                float v4 = bf2f(h2s[(size_t)(p4 & 0x1FFFF) * 64 + lane]);
                float v5 = bf2f(h2s[(size_t)(p5 & 0x1FFFF) * 64 + lane]);
                float v6 = bf2f(h2s[(size_t)(p6 & 0x1FFFF) * 64 + lane]);
                float v7 = bf2f(h2s[(size_t)(p7 & 0x1FFFF) * 64 + lane]);
                atomicAdd(&acc[(p0 >> 17) * 40 + lane], v0);
                atomicAdd(&acc[(p1 >> 17) * 40 + lane], v1);
                atomicAdd(&acc[(p2 >> 17) * 40 + lane], v2);
                atomicAdd(&acc[(p3 >> 17) * 40 + lane], v3);
                atomicAdd(&acc[(p4 >> 17) * 40 + lane], v4);
                atomicAdd(&acc[(p5 >> 17) * 40 + lane], v5);
                atomicAdd(&acc[(p6 >> 17) * 40 + lane], v6);
                atomicAdd(&acc[(p7 >> 17) * 40 + lane], v7);
            }
        }
        for (; g < nn; ++g) {
            u32 p = __shfl(pk, g, 64);
            if (act)
                atomicAdd(&acc[(p >> 17) * 40 + lane],
                          bf2f(h2s[(size_t)(p & 0x1FFFF) * 64 + lane]));
        }
    }
    __syncthreads();

    // flush: bias + log_softmax, one wave per row
    for (int r = wave; r < nr; r += 16) {
        int n = n0 + r;
        float v = act ? acc[r * 40 + lane] * dinv[n] + b2[lane] : -INFINITY;
        float m = v;
        for (int off = 32; off; off >>= 1) m = fmaxf(m, __shfl_xor(m, off, 64));
        float ex = act ? expf(v - m) : 0.f;
        float sum = ex;
        for (int off = 32; off; off >>= 1) sum += __shfl_xor(sum, off, 64);
        float lse = m + logf(sum);
        if (act) out[(size_t)n * DOUT + lane] = v - lse;
    }
}

// ---------------- launch ----------------

extern "C" void kernel_launch(void* const* d_in, const int* in_sizes, int n_in,
                              void* d_out, int out_size, void* d_ws, size_t ws_size,
                              hipStream_t stream) {
    const float* x  = (const float*)d_in[0];
    const float* W1 = (const float*)d_in[1];
    const float* b1 = (const float*)d_in[2];
    const float* W2 = (const float*)d_in[3];
    const float* b2 = (const float*)d_in[4];
    const int* eidx = (const int*)d_in[5];
    const int* srcp = eidx;
    const int* dstp = eidx + N_EDGES;
    float* out = (float*)d_out;

    char* w = (char*)d_ws;
    int* gcur    = (int*)w;   w += sizeof(int) * NB;
    float* dinv  = (float*)w; w += sizeof(float) * N_NODES;
    u32* staged  = (u32*)w;   w += sizeof(u32) * (size_t)NB * CAP;       // 8 MB
    u16* h1s     = (u16*)w;   w += sizeof(u16) * (size_t)N_NODES * DH;   // bf16 [N,64]
    float* h1    = (float*)w; w += sizeof(float) * (size_t)N_NODES * DH; // f32  [N,64]
    u16* h2s     = h1s;  // alias: h1s dead after agg1; h2s is bf16 [N,64-padded]

    hipMemsetAsync(gcur, 0, sizeof(int) * NB, stream);
    k_bin<<<(N_EDGES + EPB - 1) / EPB, 256, 0, stream>>>(srcp, dstp, gcur, staged);
    k_dinv<<<NB, 256, 0, stream>>>(gcur, staged, dinv);
    k_gemm1<<<(N_NODES + 63) / 64, 256, 0, stream>>>(x, W1, dinv, h1s);
    k_agg1<<<NB, 1024, 0, stream>>>(h1s, gcur, staged, dinv, b1, h1);
    k_gemm2<<<(N_NODES + 63) / 64, 256, 0, stream>>>(h1, W2, dinv, h2s);
    k_agg2<<<NB, 1024, 0, stream>>>(h2s, gcur, staged, dinv, b2, out);
}

// Round 4
// 245.453 us; speedup vs baseline: 4.2683x; 4.2683x over previous
//
#include <hip/hip_runtime.h>
#include <math.h>

#define N_NODES 100000
#define N_EDGES 1600000
#define DIN 128
#define DH 64
#define DOUT 40

#define NB 256        // dst buckets
#define BN 391        // nodes per bucket (256*391 = 100096 >= 100000)
#define CAP 8192      // staged capacity per bucket (mean 6250, sd ~79)
#define BIN_BLOCKS 1024
#define EPB 1563      // edges per k_bin block (1024*1563 >= 1.6M)

typedef unsigned short u16;
typedef unsigned int u32;

__device__ inline float bf2f(u16 u) {
    return __uint_as_float(((u32)u) << 16);
}
__device__ inline u16 f2bf(float f) {
    u32 u = __float_as_uint(f);
    u32 r = (u + 0x7FFFu + ((u >> 16) & 1u)) >> 16;  // RNE
    return (u16)r;
}

// ---------------- pass A: bin edges by dst bucket ----------------
// staged entry: src (17 bits) | dstlocal (9 bits) << 17

__global__ __launch_bounds__(256) void k_bin(const int* __restrict__ src,
                                             const int* __restrict__ dst,
                                             int* __restrict__ gcur,
                                             u32* __restrict__ staged) {
    __shared__ int hist[NB];
    __shared__ int base[NB];
    __shared__ int cur[NB];
    int t = threadIdx.x;
    for (int i = t; i < NB; i += 256) { hist[i] = 0; cur[i] = 0; }
    __syncthreads();
    int e0 = blockIdx.x * EPB;
    int e1 = e0 + EPB; if (e1 > N_EDGES) e1 = N_EDGES;
    for (int e = e0 + t; e < e1; e += 256)
        atomicAdd(&hist[dst[e] / BN], 1);
    __syncthreads();
    for (int i = t; i < NB; i += 256) {
        int h = hist[i];
        base[i] = h ? atomicAdd(&gcur[i], h) : 0;
    }
    __syncthreads();
    for (int e = e0 + t; e < e1; e += 256) {
        int d = dst[e], s = src[e];
        int b = d / BN;
        int dl = d - b * BN;
        int r = base[b] + atomicAdd(&cur[b], 1);
        if (r < CAP) staged[(size_t)b * CAP + r] = (u32)s | ((u32)dl << 17);
    }
}

// ---------------- pass B: per-bucket CSR build entirely in LDS ----------------
// outputs: csr (global src ids, grouped by dst), rs[n], deg[n], dinv[n]

__global__ __launch_bounds__(256) void k_csr(const int* __restrict__ gcur,
                                             const u32* __restrict__ staged,
                                             int* __restrict__ csr,
                                             int* __restrict__ rs,
                                             int* __restrict__ deg,
                                             float* __restrict__ dinv) {
    __shared__ u32 sedge[CAP];   // 32 KB
    __shared__ int lcsr[CAP];    // 32 KB
    __shared__ int hist[BN];
    __shared__ int lrs[BN];
    __shared__ int cur[BN];
    __shared__ int sbuf[256];
    int b = blockIdx.x, t = threadIdx.x;

    // bucket base = sum of clamped counts of buckets < b (block reduce)
    int part = 0;
    for (int i = t; i < b; i += 256) {
        int c = gcur[i]; if (c > CAP) c = CAP;
        part += c;
    }
    sbuf[t] = part;
    __syncthreads();
    for (int off = 128; off; off >>= 1) {
        if (t < off) sbuf[t] += sbuf[t + off];
        __syncthreads();
    }
    int base_ = sbuf[0];
    __syncthreads();

    int cnt = gcur[b]; if (cnt > CAP) cnt = CAP;
    for (int i = t; i < BN; i += 256) hist[i] = 0;
    for (int i = t; i < cnt; i += 256) sedge[i] = staged[(size_t)b * CAP + i];
    __syncthreads();
    for (int i = t; i < cnt; i += 256) atomicAdd(&hist[sedge[i] >> 17], 1);
    __syncthreads();

    // exclusive scan of hist[0..BN) (512-wide, 2 elems/thread)
    int v0 = (2 * t < BN) ? hist[2 * t] : 0;
    int v1 = (2 * t + 1 < BN) ? hist[2 * t + 1] : 0;
    int s = v0 + v1;
    sbuf[t] = s;
    __syncthreads();
    for (int off = 1; off < 256; off <<= 1) {
        int add = (t >= off) ? sbuf[t - off] : 0;
        __syncthreads();
        sbuf[t] += add;
        __syncthreads();
    }
    int excl = sbuf[t] - s;
    if (2 * t < BN)     { lrs[2 * t] = excl;      cur[2 * t] = excl; }
    if (2 * t + 1 < BN) { lrs[2 * t + 1] = excl + v0; cur[2 * t + 1] = excl + v0; }
    __syncthreads();

    // fill local CSR (random writes stay in LDS)
    for (int i = t; i < cnt; i += 256) {
        u32 p = sedge[i];
        int pos = atomicAdd(&cur[p >> 17], 1);
        lcsr[pos] = (int)(p & 0x1FFFF);
    }
    __syncthreads();

    // coalesced writeout
    for (int i = t; i < cnt; i += 256) csr[base_ + i] = lcsr[i];
    int n0 = b * BN;
    for (int i = t; i < BN; i += 256) {
        int n = n0 + i;
        if (n < N_NODES) {
            int dg = hist[i];
            rs[n] = base_ + lrs[i];
            deg[n] = dg;
            dinv[n] = rsqrtf((float)dg + 1.0f);
        }
    }
}

// ---------------- GEMM1: h1s = bf16((x @ W1) * dinv[row])  [N,64] ----------------

__global__ __launch_bounds__(256) void k_gemm1(const float* __restrict__ x,
                                               const float* __restrict__ W1,
                                               const float* __restrict__ dinv,
                                               u16* __restrict__ h1s) {
    __shared__ float xs[64 * 132];
    __shared__ float wsh[DIN * DH];
    int t = threadIdx.x;
    int row0 = blockIdx.x * 64;

    for (int it = 0; it < 8; ++it) {
        int idx = (it * 256 + t) * 4;
        int r = idx >> 7, c = idx & 127;
        float4 v = make_float4(0.f, 0.f, 0.f, 0.f);
        if (row0 + r < N_NODES) v = *(const float4*)&x[(size_t)(row0 + r) * DIN + c];
        *(float4*)&xs[r * 132 + c] = v;
    }
    for (int it = 0; it < 8; ++it) {
        int idx = (it * 256 + t) * 4;
        *(float4*)&wsh[idx] = *(const float4*)&W1[idx];
    }
    __syncthreads();

    int tr = t & 15;
    int tc = t >> 4;
    float acc[4][4] = {};
    for (int k = 0; k < DIN; ++k) {
        float4 wv = *(const float4*)&wsh[k * DH + tr * 4];
#pragma unroll
        for (int i = 0; i < 4; ++i) {
            float xv = xs[(tc * 4 + i) * 132 + k];
            acc[i][0] += xv * wv.x;
            acc[i][1] += xv * wv.y;
            acc[i][2] += xv * wv.z;
            acc[i][3] += xv * wv.w;
        }
    }
#pragma unroll
    for (int i = 0; i < 4; ++i) {
        int row = row0 + tc * 4 + i;
        if (row < N_NODES) {
            float dv = dinv[row];
            ushort4 o;
            o.x = f2bf(acc[i][0] * dv);
            o.y = f2bf(acc[i][1] * dv);
            o.z = f2bf(acc[i][2] * dv);
            o.w = f2bf(acc[i][3] * dv);
            *(ushort4*)&h1s[(size_t)row * DH + tr * 4] = o;
        }
    }
}

// ---------------- agg1 (pull): h1 = relu(dinv*(sum h1s[src] + h1s[n]) + b1) ----------------
// one 64-lane wave per node; indices via lane-load + shfl, MLP x8.

__global__ __launch_bounds__(256) void k_agg1(const u16* __restrict__ h1s,
                                              const int* __restrict__ rs,
                                              const int* __restrict__ deg,
                                              const int* __restrict__ csr,
                                              const float* __restrict__ dinv,
                                              const float* __restrict__ b1,
                                              float* __restrict__ h1) {
    int node = blockIdx.x * 4 + (threadIdx.x >> 6);
    int lane = threadIdx.x & 63;
    if (node >= N_NODES) return;
    int s0 = rs[node];
    int d = deg[node];
    float a0 = bf2f(h1s[(size_t)node * DH + lane]);  // self-loop term
    float a1 = 0.f, a2 = 0.f, a3 = 0.f, a4 = 0.f, a5 = 0.f, a6 = 0.f, a7 = 0.f;
    for (int base = 0; base < d; base += 64) {
        int nn = d - base; if (nn > 64) nn = 64;
        int myidx = (lane < nn) ? csr[s0 + base + lane] : 0;
        int j = 0;
        for (; j + 8 <= nn; j += 8) {
            int i0 = __shfl(myidx, j + 0, 64); int i1 = __shfl(myidx, j + 1, 64);
            int i2 = __shfl(myidx, j + 2, 64); int i3 = __shfl(myidx, j + 3, 64);
            int i4 = __shfl(myidx, j + 4, 64); int i5 = __shfl(myidx, j + 5, 64);
            int i6 = __shfl(myidx, j + 6, 64); int i7 = __shfl(myidx, j + 7, 64);
            a0 += bf2f(h1s[(size_t)i0 * DH + lane]);
            a1 += bf2f(h1s[(size_t)i1 * DH + lane]);
            a2 += bf2f(h1s[(size_t)i2 * DH + lane]);
            a3 += bf2f(h1s[(size_t)i3 * DH + lane]);
            a4 += bf2f(h1s[(size_t)i4 * DH + lane]);
            a5 += bf2f(h1s[(size_t)i5 * DH + lane]);
            a6 += bf2f(h1s[(size_t)i6 * DH + lane]);
            a7 += bf2f(h1s[(size_t)i7 * DH + lane]);
        }
        for (; j < nn; ++j) {
            int s = __shfl(myidx, j, 64);
            a0 += bf2f(h1s[(size_t)s * DH + lane]);
        }
    }
    float acc = ((a0 + a1) + (a2 + a3)) + ((a4 + a5) + (a6 + a7));
    float v = acc * dinv[node] + b1[lane];
    h1[(size_t)node * DH + lane] = fmaxf(v, 0.f);
}

// ---------------- GEMM2: h2s = bf16((h1 @ W2) * dinv[row])  [N,64-padded] ----------------

__global__ __launch_bounds__(256) void k_gemm2(const float* __restrict__ h1,
                                               const float* __restrict__ W2,
                                               const float* __restrict__ dinv,
                                               u16* __restrict__ h2s) {
    __shared__ float xs[64 * 68];
    __shared__ float wsh[DH * DOUT];
    int t = threadIdx.x;
    int row0 = blockIdx.x * 64;

    for (int it = 0; it < 4; ++it) {
        int idx = (it * 256 + t) * 4;
        int r = idx >> 6, c = idx & 63;
        float4 v = make_float4(0.f, 0.f, 0.f, 0.f);
        if (row0 + r < N_NODES) v = *(const float4*)&h1[(size_t)(row0 + r) * DH + c];
        *(float4*)&xs[r * 68 + c] = v;
    }
    for (int idx = t * 4; idx < DH * DOUT; idx += 1024) {
        *(float4*)&wsh[idx] = *(const float4*)&W2[idx];
    }
    __syncthreads();

    int fg = t & 7;
    int rg = t >> 3;
    float acc[2][5] = {};
    for (int k = 0; k < DH; ++k) {
        float x0 = xs[(rg * 2 + 0) * 68 + k];
        float x1 = xs[(rg * 2 + 1) * 68 + k];
#pragma unroll
        for (int j = 0; j < 5; ++j) {
            float w = wsh[k * DOUT + fg * 5 + j];
            acc[0][j] += x0 * w;
            acc[1][j] += x1 * w;
        }
    }
#pragma unroll
    for (int i = 0; i < 2; ++i) {
        int row = row0 + rg * 2 + i;
        if (row < N_NODES) {
            float dv = dinv[row];
#pragma unroll
            for (int j = 0; j < 5; ++j)
                h2s[(size_t)row * 64 + fg * 5 + j] = f2bf(acc[i][j] * dv);
        }
    }
}

// ---------------- agg2 (pull) + bias + log_softmax ----------------
// h2s rows padded to 64 bf16 (128 B) so a gather never crosses a cacheline.

__global__ __launch_bounds__(256) void k_agg2(const u16* __restrict__ h2s,
                                              const int* __restrict__ rs,
                                              const int* __restrict__ deg,
                                              const int* __restrict__ csr,
                                              const float* __restrict__ dinv,
                                              const float* __restrict__ b2,
                                              float* __restrict__ out) {
    int node = blockIdx.x * 4 + (threadIdx.x >> 6);
    int lane = threadIdx.x & 63;
    if (node >= N_NODES) return;
    int s0 = rs[node];
    int d = deg[node];
    bool act = lane < DOUT;
    float a0 = act ? bf2f(h2s[(size_t)node * 64 + lane]) : 0.f;  // self-loop
    float a1 = 0.f, a2 = 0.f, a3 = 0.f, a4 = 0.f, a5 = 0.f, a6 = 0.f, a7 = 0.f;
    for (int base = 0; base < d; base += 64) {
        int nn = d - base; if (nn > 64) nn = 64;
        int myidx = (lane < nn) ? csr[s0 + base + lane] : 0;
        int j = 0;
        for (; j + 8 <= nn; j += 8) {
            int i0 = __shfl(myidx, j + 0, 64); int i1 = __shfl(myidx, j + 1, 64);
            int i2 = __shfl(myidx, j + 2, 64); int i3 = __shfl(myidx, j + 3, 64);
            int i4 = __shfl(myidx, j + 4, 64); int i5 = __shfl(myidx, j + 5, 64);
            int i6 = __shfl(myidx, j + 6, 64); int i7 = __shfl(myidx, j + 7, 64);
            if (act) {
                a0 += bf2f(h2s[(size_t)i0 * 64 + lane]);
                a1 += bf2f(h2s[(size_t)i1 * 64 + lane]);
                a2 += bf2f(h2s[(size_t)i2 * 64 + lane]);
                a3 += bf2f(h2s[(size_t)i3 * 64 + lane]);
                a4 += bf2f(h2s[(size_t)i4 * 64 + lane]);
                a5 += bf2f(h2s[(size_t)i5 * 64 + lane]);
                a6 += bf2f(h2s[(size_t)i6 * 64 + lane]);
                a7 += bf2f(h2s[(size_t)i7 * 64 + lane]);
            }
        }
        for (; j < nn; ++j) {
            int s = __shfl(myidx, j, 64);
            if (act) a0 += bf2f(h2s[(size_t)s * 64 + lane]);
        }
    }
    float acc = ((a0 + a1) + (a2 + a3)) + ((a4 + a5) + (a6 + a7));
    float v = act ? acc * dinv[node] + b2[lane] : -INFINITY;
    float m = v;
    for (int off = 32; off; off >>= 1) m = fmaxf(m, __shfl_xor(m, off, 64));
    float ex = act ? expf(v - m) : 0.f;
    float sum = ex;
    for (int off = 32; off; off >>= 1) sum += __shfl_xor(sum, off, 64);
    float lse = m + logf(sum);
    if (act) out[(size_t)node * DOUT + lane] = v - lse;
}

// ---------------- launch ----------------

extern "C" void kernel_launch(void* const* d_in, const int* in_sizes, int n_in,
                              void* d_out, int out_size, void* d_ws, size_t ws_size,
                              hipStream_t stream) {
    const float* x  = (const float*)d_in[0];
    const float* W1 = (const float*)d_in[1];
    const float* b1 = (const float*)d_in[2];
    const float* W2 = (const float*)d_in[3];
    const float* b2 = (const float*)d_in[4];
    const int* eidx = (const int*)d_in[5];
    const int* srcp = eidx;
    const int* dstp = eidx + N_EDGES;
    float* out = (float*)d_out;

    char* w = (char*)d_ws;
    int* gcur    = (int*)w;   w += sizeof(int) * NB;
    float* dinv  = (float*)w; w += sizeof(float) * N_NODES;
    int* rs      = (int*)w;   w += sizeof(int) * N_NODES;
    int* deg     = (int*)w;   w += sizeof(int) * N_NODES;
    u32* staged  = (u32*)w;   w += sizeof(u32) * (size_t)NB * CAP;       // 8 MB
    int* csr     = (int*)w;   w += sizeof(int) * N_EDGES;                // 6.4 MB
    u16* h1s     = (u16*)w;   w += sizeof(u16) * (size_t)N_NODES * DH;   // bf16 [N,64]
    float* h1    = (float*)w; w += sizeof(float) * (size_t)N_NODES * DH; // f32  [N,64]
    u16* h2s     = h1s;  // alias: h1s dead after agg1; h2s is bf16 [N,64-padded]

    hipMemsetAsync(gcur, 0, sizeof(int) * NB, stream);
    k_bin<<<BIN_BLOCKS, 256, 0, stream>>>(srcp, dstp, gcur, staged);
    k_csr<<<NB, 256, 0, stream>>>(gcur, staged, csr, rs, deg, dinv);
    k_gemm1<<<(N_NODES + 63) / 64, 256, 0, stream>>>(x, W1, dinv, h1s);
    k_agg1<<<(N_NODES + 3) / 4, 256, 0, stream>>>(h1s, rs, deg, csr, dinv, b1, h1);
    k_gemm2<<<(N_NODES + 63) / 64, 256, 0, stream>>>(h1, W2, dinv, h2s);
    k_agg2<<<(N_NODES + 3) / 4, 256, 0, stream>>>(h2s, rs, deg, csr, dinv, b2, out);
}

// Round 5
// 228.042 us; speedup vs baseline: 4.5942x; 1.0764x over previous
//
#include <hip/hip_runtime.h>
#include <math.h>

#define N_NODES 100000
#define N_EDGES 1600000
#define DIN 128
#define DH 64
#define DOUT 40

#define NB 256        // dst buckets
#define BN 391        // nodes per bucket (256*391 = 100096 >= 100000)
#define CAP 8192      // staged capacity per bucket (mean 6250, sd ~79)
#define BIN_BLOCKS 512
#define EPB 3125      // edges per k_bin block (512*3125 = 1.6M)

typedef unsigned short u16;
typedef unsigned int u32;

__device__ inline float bf2f(u16 u) {
    return __uint_as_float(((u32)u) << 16);
}
__device__ inline u16 f2bf(float f) {
    u32 u = __float_as_uint(f);
    u32 r = (u + 0x7FFFu + ((u >> 16) & 1u)) >> 16;  // RNE
    return (u16)r;
}

// ---------------- pass A: bin edges by dst bucket ----------------
// staged entry: src (17 bits) | dstlocal (9 bits) << 17

__global__ __launch_bounds__(256) void k_bin(const int* __restrict__ src,
                                             const int* __restrict__ dst,
                                             int* __restrict__ gcur,
                                             u32* __restrict__ staged) {
    __shared__ int hist[NB];
    __shared__ int base[NB];
    __shared__ int cur[NB];
    int t = threadIdx.x;
    for (int i = t; i < NB; i += 256) { hist[i] = 0; cur[i] = 0; }
    __syncthreads();
    int e0 = blockIdx.x * EPB;
    int e1 = e0 + EPB; if (e1 > N_EDGES) e1 = N_EDGES;
    for (int e = e0 + t; e < e1; e += 256)
        atomicAdd(&hist[dst[e] / BN], 1);
    __syncthreads();
    for (int i = t; i < NB; i += 256) {
        int h = hist[i];
        base[i] = h ? atomicAdd(&gcur[i], h) : 0;
    }
    __syncthreads();
    for (int e = e0 + t; e < e1; e += 256) {
        int d = dst[e], s = src[e];
        int b = d / BN;
        int dl = d - b * BN;
        int r = base[b] + atomicAdd(&cur[b], 1);
        if (r < CAP) staged[(size_t)b * CAP + r] = (u32)s | ((u32)dl << 17);
    }
}

// ---------------- pass B: per-bucket CSR build entirely in LDS ----------------
// outputs: csr (global src ids, grouped by dst), rs[n], deg[n], dinv[n]

__global__ __launch_bounds__(256) void k_csr(const int* __restrict__ gcur,
                                             const u32* __restrict__ staged,
                                             int* __restrict__ csr,
                                             int* __restrict__ rs,
                                             int* __restrict__ deg,
                                             float* __restrict__ dinv) {
    __shared__ u32 sedge[CAP];   // 32 KB
    __shared__ int lcsr[CAP];    // 32 KB
    __shared__ int hist[BN];
    __shared__ int lrs[BN];
    __shared__ int cur[BN];
    __shared__ int sbuf[256];
    int b = blockIdx.x, t = threadIdx.x;

    // bucket base = sum of clamped counts of buckets < b (block reduce)
    int part = 0;
    for (int i = t; i < b; i += 256) {
        int c = gcur[i]; if (c > CAP) c = CAP;
        part += c;
    }
    sbuf[t] = part;
    __syncthreads();
    for (int off = 128; off; off >>= 1) {
        if (t < off) sbuf[t] += sbuf[t + off];
        __syncthreads();
    }
    int base_ = sbuf[0];
    __syncthreads();

    int cnt = gcur[b]; if (cnt > CAP) cnt = CAP;
    for (int i = t; i < BN; i += 256) hist[i] = 0;
    for (int i = t; i < cnt; i += 256) sedge[i] = staged[(size_t)b * CAP + i];
    __syncthreads();
    for (int i = t; i < cnt; i += 256) atomicAdd(&hist[sedge[i] >> 17], 1);
    __syncthreads();

    // exclusive scan of hist[0..BN) (2 elems/thread)
    int v0 = (2 * t < BN) ? hist[2 * t] : 0;
    int v1 = (2 * t + 1 < BN) ? hist[2 * t + 1] : 0;
    int s = v0 + v1;
    sbuf[t] = s;
    __syncthreads();
    for (int off = 1; off < 256; off <<= 1) {
        int add = (t >= off) ? sbuf[t - off] : 0;
        __syncthreads();
        sbuf[t] += add;
        __syncthreads();
    }
    int excl = sbuf[t] - s;
    if (2 * t < BN)     { lrs[2 * t] = excl;      cur[2 * t] = excl; }
    if (2 * t + 1 < BN) { lrs[2 * t + 1] = excl + v0; cur[2 * t + 1] = excl + v0; }
    __syncthreads();

    // fill local CSR (random writes stay in LDS)
    for (int i = t; i < cnt; i += 256) {
        u32 p = sedge[i];
        int pos = atomicAdd(&cur[p >> 17], 1);
        lcsr[pos] = (int)(p & 0x1FFFF);
    }
    __syncthreads();

    // coalesced writeout
    for (int i = t; i < cnt; i += 256) csr[base_ + i] = lcsr[i];
    int n0 = b * BN;
    for (int i = t; i < BN; i += 256) {
        int n = n0 + i;
        if (n < N_NODES) {
            int dg = hist[i];
            rs[n] = base_ + lrs[i];
            deg[n] = dg;
            dinv[n] = rsqrtf((float)dg + 1.0f);
        }
    }
}

// ---------------- GEMM1: h1s = bf16((x @ W1) * dinv[row])  [N,64] ----------------

__global__ __launch_bounds__(256) void k_gemm1(const float* __restrict__ x,
                                               const float* __restrict__ W1,
                                               const float* __restrict__ dinv,
                                               u16* __restrict__ h1s) {
    __shared__ float xs[64 * 132];
    __shared__ float wsh[DIN * DH];
    int t = threadIdx.x;
    int row0 = blockIdx.x * 64;

    for (int it = 0; it < 8; ++it) {
        int idx = (it * 256 + t) * 4;
        int r = idx >> 7, c = idx & 127;
        float4 v = make_float4(0.f, 0.f, 0.f, 0.f);
        if (row0 + r < N_NODES) v = *(const float4*)&x[(size_t)(row0 + r) * DIN + c];
        *(float4*)&xs[r * 132 + c] = v;
    }
    for (int it = 0; it < 8; ++it) {
        int idx = (it * 256 + t) * 4;
        *(float4*)&wsh[idx] = *(const float4*)&W1[idx];
    }
    __syncthreads();

    int tr = t & 15;
    int tc = t >> 4;
    float acc[4][4] = {};
    for (int k = 0; k < DIN; ++k) {
        float4 wv = *(const float4*)&wsh[k * DH + tr * 4];
#pragma unroll
        for (int i = 0; i < 4; ++i) {
            float xv = xs[(tc * 4 + i) * 132 + k];
            acc[i][0] += xv * wv.x;
            acc[i][1] += xv * wv.y;
            acc[i][2] += xv * wv.z;
            acc[i][3] += xv * wv.w;
        }
    }
#pragma unroll
    for (int i = 0; i < 4; ++i) {
        int row = row0 + tc * 4 + i;
        if (row < N_NODES) {
            float dv = dinv[row];
            ushort4 o;
            o.x = f2bf(acc[i][0] * dv);
            o.y = f2bf(acc[i][1] * dv);
            o.z = f2bf(acc[i][2] * dv);
            o.w = f2bf(acc[i][3] * dv);
            *(ushort4*)&h1s[(size_t)row * DH + tr * 4] = o;
        }
    }
}

// ---------------- agg1 (pull): h1 = relu(dinv*(sum h1s[src] + h1s[n]) + b1) ----------------
// one 64-lane wave per node. CSR indices are wave-uniform -> scalar loads (SALU);
// gather = global_load_ushort with uniform SGPR row base + per-lane offset.

__global__ __launch_bounds__(256) void k_agg1(const u16* __restrict__ h1s,
                                              const int* __restrict__ rs,
                                              const int* __restrict__ deg,
                                              const int* __restrict__ csr,
                                              const float* __restrict__ dinv,
                                              const float* __restrict__ b1,
                                              float* __restrict__ h1) {
    int node = blockIdx.x * 4 + (threadIdx.x >> 6);
    int lane = threadIdx.x & 63;
    if (node >= N_NODES) return;
    int s0 = __builtin_amdgcn_readfirstlane(rs[node]);
    int d  = __builtin_amdgcn_readfirstlane(deg[node]);
    float a0 = bf2f(h1s[(size_t)node * DH + lane]);  // self-loop term
    float a1 = 0.f, a2 = 0.f, a3 = 0.f, a4 = 0.f, a5 = 0.f, a6 = 0.f, a7 = 0.f;
    int j = 0;
    for (; j + 8 <= d; j += 8) {
        int i0 = csr[s0 + j + 0]; int i1 = csr[s0 + j + 1];
        int i2 = csr[s0 + j + 2]; int i3 = csr[s0 + j + 3];
        int i4 = csr[s0 + j + 4]; int i5 = csr[s0 + j + 5];
        int i6 = csr[s0 + j + 6]; int i7 = csr[s0 + j + 7];
        a0 += bf2f(h1s[(size_t)i0 * DH + lane]);
        a1 += bf2f(h1s[(size_t)i1 * DH + lane]);
        a2 += bf2f(h1s[(size_t)i2 * DH + lane]);
        a3 += bf2f(h1s[(size_t)i3 * DH + lane]);
        a4 += bf2f(h1s[(size_t)i4 * DH + lane]);
        a5 += bf2f(h1s[(size_t)i5 * DH + lane]);
        a6 += bf2f(h1s[(size_t)i6 * DH + lane]);
        a7 += bf2f(h1s[(size_t)i7 * DH + lane]);
    }
    for (; j < d; ++j) {
        int s = csr[s0 + j];
        a0 += bf2f(h1s[(size_t)s * DH + lane]);
    }
    float acc = ((a0 + a1) + (a2 + a3)) + ((a4 + a5) + (a6 + a7));
    float v = acc * dinv[node] + b1[lane];
    h1[(size_t)node * DH + lane] = fmaxf(v, 0.f);
}

// ---------------- GEMM2: h2s = bf16((h1 @ W2) * dinv[row])  [N,64-padded] ----------------

__global__ __launch_bounds__(256) void k_gemm2(const float* __restrict__ h1,
                                               const float* __restrict__ W2,
                                               const float* __restrict__ dinv,
                                               u16* __restrict__ h2s) {
    __shared__ float xs[64 * 68];
    __shared__ float wsh[DH * DOUT];
    int t = threadIdx.x;
    int row0 = blockIdx.x * 64;

    for (int it = 0; it < 4; ++it) {
        int idx = (it * 256 + t) * 4;
        int r = idx >> 6, c = idx & 63;
        float4 v = make_float4(0.f, 0.f, 0.f, 0.f);
        if (row0 + r < N_NODES) v = *(const float4*)&h1[(size_t)(row0 + r) * DH + c];
        *(float4*)&xs[r * 68 + c] = v;
    }
    for (int idx = t * 4; idx < DH * DOUT; idx += 1024) {
        *(float4*)&wsh[idx] = *(const float4*)&W2[idx];
    }
    __syncthreads();

    int fg = t & 7;
    int rg = t >> 3;
    float acc[2][5] = {};
    for (int k = 0; k < DH; ++k) {
        float x0 = xs[(rg * 2 + 0) * 68 + k];
        float x1 = xs[(rg * 2 + 1) * 68 + k];
#pragma unroll
        for (int j = 0; j < 5; ++j) {
            float w = wsh[k * DOUT + fg * 5 + j];
            acc[0][j] += x0 * w;
            acc[1][j] += x1 * w;
        }
    }
#pragma unroll
    for (int i = 0; i < 2; ++i) {
        int row = row0 + rg * 2 + i;
        if (row < N_NODES) {
            float dv = dinv[row];
#pragma unroll
            for (int j = 0; j < 5; ++j)
                h2s[(size_t)row * 64 + fg * 5 + j] = f2bf(acc[i][j] * dv);
        }
    }
}

// ---------------- agg2 (pull) + bias + log_softmax ----------------
// h2s rows padded to 64 bf16 (128 B); scalar CSR index loads as in agg1.

__global__ __launch_bounds__(256) void k_agg2(const u16* __restrict__ h2s,
                                              const int* __restrict__ rs,
                                              const int* __restrict__ deg,
                                              const int* __restrict__ csr,
                                              const float* __restrict__ dinv,
                                              const float* __restrict__ b2,
                                              float* __restrict__ out) {
    int node = blockIdx.x * 4 + (threadIdx.x >> 6);
    int lane = threadIdx.x & 63;
    if (node >= N_NODES) return;
    int s0 = __builtin_amdgcn_readfirstlane(rs[node]);
    int d  = __builtin_amdgcn_readfirstlane(deg[node]);
    bool act = lane < DOUT;
    float a0 = act ? bf2f(h2s[(size_t)node * 64 + lane]) : 0.f;  // self-loop
    float a1 = 0.f, a2 = 0.f, a3 = 0.f, a4 = 0.f, a5 = 0.f, a6 = 0.f, a7 = 0.f;
    int lane2 = act ? lane : 0;  // keep inactive lanes in-bounds
    int j = 0;
    for (; j + 8 <= d; j += 8) {
        int i0 = csr[s0 + j + 0]; int i1 = csr[s0 + j + 1];
        int i2 = csr[s0 + j + 2]; int i3 = csr[s0 + j + 3];
        int i4 = csr[s0 + j + 4]; int i5 = csr[s0 + j + 5];
        int i6 = csr[s0 + j + 6]; int i7 = csr[s0 + j + 7];
        float v0 = bf2f(h2s[(size_t)i0 * 64 + lane2]);
        float v1 = bf2f(h2s[(size_t)i1 * 64 + lane2]);
        float v2 = bf2f(h2s[(size_t)i2 * 64 + lane2]);
        float v3 = bf2f(h2s[(size_t)i3 * 64 + lane2]);
        float v4 = bf2f(h2s[(size_t)i4 * 64 + lane2]);
        float v5 = bf2f(h2s[(size_t)i5 * 64 + lane2]);
        float v6 = bf2f(h2s[(size_t)i6 * 64 + lane2]);
        float v7 = bf2f(h2s[(size_t)i7 * 64 + lane2]);
        a0 += v0; a1 += v1; a2 += v2; a3 += v3;
        a4 += v4; a5 += v5; a6 += v6; a7 += v7;
    }
    for (; j < d; ++j) {
        int s = csr[s0 + j];
        a0 += bf2f(h2s[(size_t)s * 64 + lane2]);
    }
    float acc = ((a0 + a1) + (a2 + a3)) + ((a4 + a5) + (a6 + a7));
    float v = act ? acc * dinv[node] + b2[lane] : -INFINITY;
    float m = v;
    for (int off = 32; off; off >>= 1) m = fmaxf(m, __shfl_xor(m, off, 64));
    float ex = act ? expf(v - m) : 0.f;
    float sum = ex;
    for (int off = 32; off; off >>= 1) sum += __shfl_xor(sum, off, 64);
    float lse = m + logf(sum);
    if (act) out[(size_t)node * DOUT + lane] = v - lse;
}

// ---------------- launch ----------------

extern "C" void kernel_launch(void* const* d_in, const int* in_sizes, int n_in,
                              void* d_out, int out_size, void* d_ws, size_t ws_size,
                              hipStream_t stream) {
    const float* x  = (const float*)d_in[0];
    const float* W1 = (const float*)d_in[1];
    const float* b1 = (const float*)d_in[2];
    const float* W2 = (const float*)d_in[3];
    const float* b2 = (const float*)d_in[4];
    const int* eidx = (const int*)d_in[5];
    const int* srcp = eidx;
    const int* dstp = eidx + N_EDGES;
    float* out = (float*)d_out;

    char* w = (char*)d_ws;
    int* gcur    = (int*)w;   w += sizeof(int) * NB;
    float* dinv  = (float*)w; w += sizeof(float) * N_NODES;
    int* rs      = (int*)w;   w += sizeof(int) * N_NODES;
    int* deg     = (int*)w;   w += sizeof(int) * N_NODES;
    u32* staged  = (u32*)w;   w += sizeof(u32) * (size_t)NB * CAP;       // 8 MB
    int* csr     = (int*)w;   w += sizeof(int) * N_EDGES;                // 6.4 MB
    u16* h1s     = (u16*)w;   w += sizeof(u16) * (size_t)N_NODES * DH;   // bf16 [N,64]
    float* h1    = (float*)w; w += sizeof(float) * (size_t)N_NODES * DH; // f32  [N,64]
    u16* h2s     = h1s;  // alias: h1s dead after agg1; h2s is bf16 [N,64-padded]

    hipMemsetAsync(gcur, 0, sizeof(int) * NB, stream);
    k_bin<<<BIN_BLOCKS, 256, 0, stream>>>(srcp, dstp, gcur, staged);
    k_csr<<<NB, 256, 0, stream>>>(gcur, staged, csr, rs, deg, dinv);
    k_gemm1<<<(N_NODES + 63) / 64, 256, 0, stream>>>(x, W1, dinv, h1s);
    k_agg1<<<(N_NODES + 3) / 4, 256, 0, stream>>>(h1s, rs, deg, csr, dinv, b1, h1);
    k_gemm2<<<(N_NODES + 63) / 64, 256, 0, stream>>>(h1, W2, dinv, h2s);
    k_agg2<<<(N_NODES + 3) / 4, 256, 0, stream>>>(h2s, rs, deg, csr, dinv, b2, out);
}

// Round 6
// 221.953 us; speedup vs baseline: 4.7202x; 1.0274x over previous
//
#include <hip/hip_runtime.h>
#include <math.h>

#define N_NODES 100000
#define N_EDGES 1600000
#define DIN 128
#define DH 64
#define DOUT 40

#define NB 256        // dst buckets
#define BN 391        // nodes per bucket (256*391 = 100096 >= 100000)
#define CAP 8192      // staged capacity per bucket (mean 6250, sd ~79)
#define BIN_BLOCKS 512
#define EPB 3125      // edges per k_bin block (512*3125 = 1.6M)

typedef unsigned short u16;
typedef unsigned int u32;

__device__ inline float bf2f(u16 u) {
    return __uint_as_float(((u32)u) << 16);
}
__device__ inline u16 f2bf(float f) {
    u32 u = __float_as_uint(f);
    u32 r = (u + 0x7FFFu + ((u >> 16) & 1u)) >> 16;  // RNE
    return (u16)r;
}
// accumulate 4 bf16 packed in a uint2 into 4 f32 accumulators
__device__ inline void acc4(uint2 v, float& a0, float& a1, float& a2, float& a3) {
    a0 += __uint_as_float(v.x << 16);
    a1 += __uint_as_float(v.x & 0xffff0000u);
    a2 += __uint_as_float(v.y << 16);
    a3 += __uint_as_float(v.y & 0xffff0000u);
}

// ---------------- pass A: bin edges by dst bucket ----------------
// staged entry: src (17 bits) | dstlocal (9 bits) << 17

__global__ __launch_bounds__(256) void k_bin(const int* __restrict__ src,
                                             const int* __restrict__ dst,
                                             int* __restrict__ gcur,
                                             u32* __restrict__ staged) {
    __shared__ int hist[NB];
    __shared__ int base[NB];
    __shared__ int cur[NB];
    int t = threadIdx.x;
    for (int i = t; i < NB; i += 256) { hist[i] = 0; cur[i] = 0; }
    __syncthreads();
    int e0 = blockIdx.x * EPB;
    int e1 = e0 + EPB; if (e1 > N_EDGES) e1 = N_EDGES;
    for (int e = e0 + t; e < e1; e += 256)
        atomicAdd(&hist[dst[e] / BN], 1);
    __syncthreads();
    for (int i = t; i < NB; i += 256) {
        int h = hist[i];
        base[i] = h ? atomicAdd(&gcur[i], h) : 0;
    }
    __syncthreads();
    for (int e = e0 + t; e < e1; e += 256) {
        int d = dst[e], s = src[e];
        int b = d / BN;
        int dl = d - b * BN;
        int r = base[b] + atomicAdd(&cur[b], 1);
        if (r < CAP) staged[(size_t)b * CAP + r] = (u32)s | ((u32)dl << 17);
    }
}

// ---------------- pass B: per-bucket CSR build entirely in LDS ----------------
// outputs: csr (grouped by dst), meta[n] = {rowstart, deg, dinv_bits, 0}, dinv[n]

__global__ __launch_bounds__(256) void k_csr(const int* __restrict__ gcur,
                                             const u32* __restrict__ staged,
                                             int* __restrict__ csr,
                                             int4* __restrict__ meta,
                                             float* __restrict__ dinv) {
    __shared__ u32 sedge[CAP];   // 32 KB
    __shared__ int lcsr[CAP];    // 32 KB
    __shared__ int hist[BN];
    __shared__ int lrs[BN];
    __shared__ int cur[BN];
    __shared__ int sbuf[256];
    int b = blockIdx.x, t = threadIdx.x;

    // bucket base = sum of clamped counts of buckets < b (block reduce)
    int part = 0;
    for (int i = t; i < b; i += 256) {
        int c = gcur[i]; if (c > CAP) c = CAP;
        part += c;
    }
    sbuf[t] = part;
    __syncthreads();
    for (int off = 128; off; off >>= 1) {
        if (t < off) sbuf[t] += sbuf[t + off];
        __syncthreads();
    }
    int base_ = sbuf[0];
    __syncthreads();

    int cnt = gcur[b]; if (cnt > CAP) cnt = CAP;
    for (int i = t; i < BN; i += 256) hist[i] = 0;
    for (int i = t; i < cnt; i += 256) sedge[i] = staged[(size_t)b * CAP + i];
    __syncthreads();
    for (int i = t; i < cnt; i += 256) atomicAdd(&hist[sedge[i] >> 17], 1);
    __syncthreads();

    // exclusive scan of hist[0..BN) (2 elems/thread)
    int v0 = (2 * t < BN) ? hist[2 * t] : 0;
    int v1 = (2 * t + 1 < BN) ? hist[2 * t + 1] : 0;
    int s = v0 + v1;
    sbuf[t] = s;
    __syncthreads();
    for (int off = 1; off < 256; off <<= 1) {
        int add = (t >= off) ? sbuf[t - off] : 0;
        __syncthreads();
        sbuf[t] += add;
        __syncthreads();
    }
    int excl = sbuf[t] - s;
    if (2 * t < BN)     { lrs[2 * t] = excl;      cur[2 * t] = excl; }
    if (2 * t + 1 < BN) { lrs[2 * t + 1] = excl + v0; cur[2 * t + 1] = excl + v0; }
    __syncthreads();

    // fill local CSR (random writes stay in LDS)
    for (int i = t; i < cnt; i += 256) {
        u32 p = sedge[i];
        int pos = atomicAdd(&cur[p >> 17], 1);
        lcsr[pos] = (int)(p & 0x1FFFF);
    }
    __syncthreads();

    // coalesced writeout
    for (int i = t; i < cnt; i += 256) csr[base_ + i] = lcsr[i];
    int n0 = b * BN;
    for (int i = t; i < BN; i += 256) {
        int n = n0 + i;
        if (n < N_NODES) {
            int dg = hist[i];
            float dv = rsqrtf((float)dg + 1.0f);
            meta[n] = make_int4(base_ + lrs[i], dg, __float_as_int(dv), 0);
            dinv[n] = dv;
        }
    }
}

// ---------------- GEMM1: h1s = bf16((x @ W1) * dinv[row])  [N,64] ----------------

__global__ __launch_bounds__(256) void k_gemm1(const float* __restrict__ x,
                                               const float* __restrict__ W1,
                                               const float* __restrict__ dinv,
                                               u16* __restrict__ h1s) {
    __shared__ float xs[64 * 132];
    __shared__ float wsh[DIN * DH];
    int t = threadIdx.x;
    int row0 = blockIdx.x * 64;

    for (int it = 0; it < 8; ++it) {
        int idx = (it * 256 + t) * 4;
        int r = idx >> 7, c = idx & 127;
        float4 v = make_float4(0.f, 0.f, 0.f, 0.f);
        if (row0 + r < N_NODES) v = *(const float4*)&x[(size_t)(row0 + r) * DIN + c];
        *(float4*)&xs[r * 132 + c] = v;
    }
    for (int it = 0; it < 8; ++it) {
        int idx = (it * 256 + t) * 4;
        *(float4*)&wsh[idx] = *(const float4*)&W1[idx];
    }
    __syncthreads();

    int tr = t & 15;
    int tc = t >> 4;
    float acc[4][4] = {};
    for (int k = 0; k < DIN; ++k) {
        float4 wv = *(const float4*)&wsh[k * DH + tr * 4];
#pragma unroll
        for (int i = 0; i < 4; ++i) {
            float xv = xs[(tc * 4 + i) * 132 + k];
            acc[i][0] += xv * wv.x;
            acc[i][1] += xv * wv.y;
            acc[i][2] += xv * wv.z;
            acc[i][3] += xv * wv.w;
        }
    }
#pragma unroll
    for (int i = 0; i < 4; ++i) {
        int row = row0 + tc * 4 + i;
        if (row < N_NODES) {
            float dv = dinv[row];
            ushort4 o;
            o.x = f2bf(acc[i][0] * dv);
            o.y = f2bf(acc[i][1] * dv);
            o.z = f2bf(acc[i][2] * dv);
            o.w = f2bf(acc[i][3] * dv);
            *(ushort4*)&h1s[(size_t)row * DH + tr * 4] = o;
        }
    }
}

// ---------------- agg1 (pull): h1 = relu(dinv*(sum h1s[src] + h1s[n]) + b1) ----------------
// one wave per node; lane = (edge-slot es 0..3, feature-pair fp 0..15), 8 B/lane
// gathers. One VMEM instruction fetches 4 source rows. Indices broadcast via
// ds_bpermute from a single coalesced CSR vector load.

__global__ __launch_bounds__(256) void k_agg1(const u16* __restrict__ h1s,
                                              const int4* __restrict__ meta,
                                              const int* __restrict__ csr,
                                              const float* __restrict__ b1,
                                              float* __restrict__ h1) {
    int node = blockIdx.x * 4 + (threadIdx.x >> 6);
    if (node >= N_NODES) return;
    node = __builtin_amdgcn_readfirstlane(node);
    int lane = threadIdx.x & 63;
    int es = lane >> 4, fp = lane & 15;
    int4 me = meta[node];
    int s0 = me.x, d = me.y;
    float dv = __int_as_float(me.z);
    const uint2* rows = (const uint2*)h1s;  // row stride = 16 uint2
    float a0 = 0.f, a1 = 0.f, a2 = 0.f, a3 = 0.f;
    if (es == 0) acc4(rows[(u32)(node * 16 + fp)], a0, a1, a2, a3);  // self
    for (int base = 0; base < d; base += 64) {
        int nn = d - base; if (nn > 64) nn = 64;
        int myidx = (lane < nn) ? csr[s0 + base + lane] : 0;
        int j = 0;
        for (; j + 16 <= nn; j += 16) {
            int x0 = __builtin_amdgcn_ds_bpermute((j + es) * 4, myidx);
            int x1 = __builtin_amdgcn_ds_bpermute((j + 4 + es) * 4, myidx);
            int x2 = __builtin_amdgcn_ds_bpermute((j + 8 + es) * 4, myidx);
            int x3 = __builtin_amdgcn_ds_bpermute((j + 12 + es) * 4, myidx);
            uint2 v0 = rows[(u32)(x0 * 16 + fp)];
            uint2 v1 = rows[(u32)(x1 * 16 + fp)];
            uint2 v2 = rows[(u32)(x2 * 16 + fp)];
            uint2 v3 = rows[(u32)(x3 * 16 + fp)];
            acc4(v0, a0, a1, a2, a3);
            acc4(v1, a0, a1, a2, a3);
            acc4(v2, a0, a1, a2, a3);
            acc4(v3, a0, a1, a2, a3);
        }
        for (; j < nn; j += 4) {
            int x = __builtin_amdgcn_ds_bpermute((j + es) * 4, myidx);
            if (j + es < nn) acc4(rows[(u32)(x * 16 + fp)], a0, a1, a2, a3);
        }
    }
    // butterfly-reduce across the 4 edge slots
    a0 += __shfl_xor(a0, 16, 64); a1 += __shfl_xor(a1, 16, 64);
    a2 += __shfl_xor(a2, 16, 64); a3 += __shfl_xor(a3, 16, 64);
    a0 += __shfl_xor(a0, 32, 64); a1 += __shfl_xor(a1, 32, 64);
    a2 += __shfl_xor(a2, 32, 64); a3 += __shfl_xor(a3, 32, 64);
    if (es == 0) {
        float4 bv = ((const float4*)b1)[fp];
        float4 o;
        o.x = fmaxf(a0 * dv + bv.x, 0.f);
        o.y = fmaxf(a1 * dv + bv.y, 0.f);
        o.z = fmaxf(a2 * dv + bv.z, 0.f);
        o.w = fmaxf(a3 * dv + bv.w, 0.f);
        ((float4*)h1)[(u32)(node * 16 + fp)] = o;
    }
}

// ---------------- GEMM2: h2s = bf16((h1 @ W2) * dinv[row])  [N,64-padded] ----------------

__global__ __launch_bounds__(256) void k_gemm2(const float* __restrict__ h1,
                                               const float* __restrict__ W2,
                                               const float* __restrict__ dinv,
                                               u16* __restrict__ h2s) {
    __shared__ float xs[64 * 68];
    __shared__ float wsh[DH * DOUT];
    int t = threadIdx.x;
    int row0 = blockIdx.x * 64;

    for (int it = 0; it < 4; ++it) {
        int idx = (it * 256 + t) * 4;
        int r = idx >> 6, c = idx & 63;
        float4 v = make_float4(0.f, 0.f, 0.f, 0.f);
        if (row0 + r < N_NODES) v = *(const float4*)&h1[(size_t)(row0 + r) * DH + c];
        *(float4*)&xs[r * 68 + c] = v;
    }
    for (int idx = t * 4; idx < DH * DOUT; idx += 1024) {
        *(float4*)&wsh[idx] = *(const float4*)&W2[idx];
    }
    __syncthreads();

    int fg = t & 7;
    int rg = t >> 3;
    float acc[2][5] = {};
    for (int k = 0; k < DH; ++k) {
        float x0 = xs[(rg * 2 + 0) * 68 + k];
        float x1 = xs[(rg * 2 + 1) * 68 + k];
#pragma unroll
        for (int j = 0; j < 5; ++j) {
            float w = wsh[k * DOUT + fg * 5 + j];
            acc[0][j] += x0 * w;
            acc[1][j] += x1 * w;
        }
    }
#pragma unroll
    for (int i = 0; i < 2; ++i) {
        int row = row0 + rg * 2 + i;
        if (row < N_NODES) {
            float dvv = dinv[row];
#pragma unroll
            for (int j = 0; j < 5; ++j)
                h2s[(size_t)row * 64 + fg * 5 + j] = f2bf(acc[i][j] * dvv);
        }
    }
}

// ---------------- agg2 (pull) + bias + log_softmax ----------------
// same slot structure; only fp<10 (40 features) active on the load side.

__global__ __launch_bounds__(256) void k_agg2(const u16* __restrict__ h2s,
                                              const int4* __restrict__ meta,
                                              const int* __restrict__ csr,
                                              const float* __restrict__ b2,
                                              float* __restrict__ out) {
    int node = blockIdx.x * 4 + (threadIdx.x >> 6);
    if (node >= N_NODES) return;
    node = __builtin_amdgcn_readfirstlane(node);
    int lane = threadIdx.x & 63;
    int es = lane >> 4, fp = lane & 15;
    bool act = fp < 10;
    int4 me = meta[node];
    int s0 = me.x, d = me.y;
    float dv = __int_as_float(me.z);
    const uint2* rows = (const uint2*)h2s;  // padded row stride = 16 uint2
    float a0 = 0.f, a1 = 0.f, a2 = 0.f, a3 = 0.f;
    if (es == 0 && act) acc4(rows[(u32)(node * 16 + fp)], a0, a1, a2, a3);  // self
    for (int base = 0; base < d; base += 64) {
        int nn = d - base; if (nn > 64) nn = 64;
        int myidx = (lane < nn) ? csr[s0 + base + lane] : 0;
        int j = 0;
        for (; j + 16 <= nn; j += 16) {
            int x0 = __builtin_amdgcn_ds_bpermute((j + es) * 4, myidx);
            int x1 = __builtin_amdgcn_ds_bpermute((j + 4 + es) * 4, myidx);
            int x2 = __builtin_amdgcn_ds_bpermute((j + 8 + es) * 4, myidx);
            int x3 = __builtin_amdgcn_ds_bpermute((j + 12 + es) * 4, myidx);
            if (act) {
                uint2 v0 = rows[(u32)(x0 * 16 + fp)];
                uint2 v1 = rows[(u32)(x1 * 16 + fp)];
                uint2 v2 = rows[(u32)(x2 * 16 + fp)];
                uint2 v3 = rows[(u32)(x3 * 16 + fp)];
                acc4(v0, a0, a1, a2, a3);
                acc4(v1, a0, a1, a2, a3);
                acc4(v2, a0, a1, a2, a3);
                acc4(v3, a0, a1, a2, a3);
            }
        }
        for (; j < nn; j += 4) {
            int x = __builtin_amdgcn_ds_bpermute((j + es) * 4, myidx);
            if (act && j + es < nn) acc4(rows[(u32)(x * 16 + fp)], a0, a1, a2, a3);
        }
    }
    // butterfly-reduce across the 4 edge slots
    a0 += __shfl_xor(a0, 16, 64); a1 += __shfl_xor(a1, 16, 64);
    a2 += __shfl_xor(a2, 16, 64); a3 += __shfl_xor(a3, 16, 64);
    a0 += __shfl_xor(a0, 32, 64); a1 += __shfl_xor(a1, 32, 64);
    a2 += __shfl_xor(a2, 32, 64); a3 += __shfl_xor(a3, 32, 64);

    // bias + log_softmax over 40 features (10 fp groups x 4)
    float4 bv = act ? ((const float4*)b2)[fp] : make_float4(0.f, 0.f, 0.f, 0.f);
    float v0 = act ? a0 * dv + bv.x : -INFINITY;
    float v1 = act ? a1 * dv + bv.y : -INFINITY;
    float v2 = act ? a2 * dv + bv.z : -INFINITY;
    float v3 = act ? a3 * dv + bv.w : -INFINITY;
    float m = fmaxf(fmaxf(v0, v1), fmaxf(v2, v3));
    m = fmaxf(m, __shfl_xor(m, 1, 64));
    m = fmaxf(m, __shfl_xor(m, 2, 64));
    m = fmaxf(m, __shfl_xor(m, 4, 64));
    m = fmaxf(m, __shfl_xor(m, 8, 64));
    float ex = act ? (expf(v0 - m) + expf(v1 - m) + expf(v2 - m) + expf(v3 - m)) : 0.f;
    ex += __shfl_xor(ex, 1, 64);
    ex += __shfl_xor(ex, 2, 64);
    ex += __shfl_xor(ex, 4, 64);
    ex += __shfl_xor(ex, 8, 64);
    float lse = m + logf(ex);
    if (es == 0 && act) {
        float4 o = make_float4(v0 - lse, v1 - lse, v2 - lse, v3 - lse);
        *(float4*)&out[(u32)(node * 40 + fp * 4)] = o;
    }
}

// ---------------- launch ----------------

extern "C" void kernel_launch(void* const* d_in, const int* in_sizes, int n_in,
                              void* d_out, int out_size, void* d_ws, size_t ws_size,
                              hipStream_t stream) {
    const float* x  = (const float*)d_in[0];
    const float* W1 = (const float*)d_in[1];
    const float* b1 = (const float*)d_in[2];
    const float* W2 = (const float*)d_in[3];
    const float* b2 = (const float*)d_in[4];
    const int* eidx = (const int*)d_in[5];
    const int* srcp = eidx;
    const int* dstp = eidx + N_EDGES;
    float* out = (float*)d_out;

    char* w = (char*)d_ws;
    int* gcur    = (int*)w;   w += sizeof(int) * NB;
    float* dinv  = (float*)w; w += sizeof(float) * N_NODES + 48;  // keep int4 alignment
    int4* meta   = (int4*)w;  w += sizeof(int4) * N_NODES;
    u32* staged  = (u32*)w;   w += sizeof(u32) * (size_t)NB * CAP;       // 8 MB
    int* csr     = (int*)w;   w += sizeof(int) * N_EDGES;                // 6.4 MB
    u16* h1s     = (u16*)w;   w += sizeof(u16) * (size_t)N_NODES * DH;   // bf16 [N,64]
    float* h1    = (float*)w; w += sizeof(float) * (size_t)N_NODES * DH; // f32  [N,64]
    u16* h2s     = h1s;  // alias: h1s dead after agg1; h2s is bf16 [N,64-padded]

    hipMemsetAsync(gcur, 0, sizeof(int) * NB, stream);
    k_bin<<<BIN_BLOCKS, 256, 0, stream>>>(srcp, dstp, gcur, staged);
    k_csr<<<NB, 256, 0, stream>>>(gcur, staged, csr, meta, dinv);
    k_gemm1<<<(N_NODES + 63) / 64, 256, 0, stream>>>(x, W1, dinv, h1s);
    k_agg1<<<(N_NODES + 3) / 4, 256, 0, stream>>>(h1s, meta, csr, b1, h1);
    k_gemm2<<<(N_NODES + 63) / 64, 256, 0, stream>>>(h1, W2, dinv, h2s);
    k_agg2<<<(N_NODES + 3) / 4, 256, 0, stream>>>(h2s, meta, csr, b2, out);
}

// Round 7
// 217.880 us; speedup vs baseline: 4.8085x; 1.0187x over previous
//
#include <hip/hip_runtime.h>
#include <hip/hip_fp16.h>
#include <math.h>

#define N_NODES 100000
#define N_EDGES 1600000
#define DIN 128
#define DH 64
#define DOUT 40

#define NB 256        // dst buckets
#define BN 391        // nodes per bucket (256*391 = 100096 >= 100000)
#define CAP 8192      // staged capacity per bucket (mean 6250, sd ~79)
#define BIN_BLOCKS 512
#define EPB 3125      // edges per k_bin block (512*3125 = 1.6M)

typedef unsigned short u16;
typedef unsigned int u32;

__device__ inline __half2 u2h(u32 u) {
    union { u32 x; __half2 h; } c; c.x = u; return c.h;
}
__device__ inline u32 h2u(__half2 h) {
    union { __half2 h; u32 x; } c; c.h = h; return c.x;
}

// ---------------- pass A: bin edges by dst bucket ----------------
// staged entry: src (17 bits) | dstlocal (9 bits) << 17

__global__ __launch_bounds__(256) void k_bin(const int* __restrict__ src,
                                             const int* __restrict__ dst,
                                             int* __restrict__ gcur,
                                             u32* __restrict__ staged) {
    __shared__ int hist[NB];
    __shared__ int base[NB];
    __shared__ int cur[NB];
    int t = threadIdx.x;
    for (int i = t; i < NB; i += 256) { hist[i] = 0; cur[i] = 0; }
    __syncthreads();
    int e0 = blockIdx.x * EPB;
    int e1 = e0 + EPB; if (e1 > N_EDGES) e1 = N_EDGES;
    for (int e = e0 + t; e < e1; e += 256)
        atomicAdd(&hist[dst[e] / BN], 1);
    __syncthreads();
    for (int i = t; i < NB; i += 256) {
        int h = hist[i];
        base[i] = h ? atomicAdd(&gcur[i], h) : 0;
    }
    __syncthreads();
    for (int e = e0 + t; e < e1; e += 256) {
        int d = dst[e], s = src[e];
        int b = d / BN;
        int dl = d - b * BN;
        int r = base[b] + atomicAdd(&cur[b], 1);
        if (r < CAP) staged[(size_t)b * CAP + r] = (u32)s | ((u32)dl << 17);
    }
}

// ---------------- pass B: per-bucket CSR build entirely in LDS ----------------
// outputs: csr (grouped by dst), meta[n] = {rowstart, deg, dinv_bits, 0}, dinv[n]

__global__ __launch_bounds__(256) void k_csr(const int* __restrict__ gcur,
                                             const u32* __restrict__ staged,
                                             int* __restrict__ csr,
                                             int4* __restrict__ meta,
                                             float* __restrict__ dinv) {
    __shared__ u32 sedge[CAP];   // 32 KB
    __shared__ int lcsr[CAP];    // 32 KB
    __shared__ int hist[BN];
    __shared__ int lrs[BN];
    __shared__ int cur[BN];
    __shared__ int sbuf[256];
    int b = blockIdx.x, t = threadIdx.x;

    // bucket base = sum of clamped counts of buckets < b (block reduce)
    int part = 0;
    for (int i = t; i < b; i += 256) {
        int c = gcur[i]; if (c > CAP) c = CAP;
        part += c;
    }
    sbuf[t] = part;
    __syncthreads();
    for (int off = 128; off; off >>= 1) {
        if (t < off) sbuf[t] += sbuf[t + off];
        __syncthreads();
    }
    int base_ = sbuf[0];
    __syncthreads();

    int cnt = gcur[b]; if (cnt > CAP) cnt = CAP;
    for (int i = t; i < BN; i += 256) hist[i] = 0;
    for (int i = t; i < cnt; i += 256) sedge[i] = staged[(size_t)b * CAP + i];
    __syncthreads();
    for (int i = t; i < cnt; i += 256) atomicAdd(&hist[sedge[i] >> 17], 1);
    __syncthreads();

    // exclusive scan of hist[0..BN) (2 elems/thread)
    int v0 = (2 * t < BN) ? hist[2 * t] : 0;
    int v1 = (2 * t + 1 < BN) ? hist[2 * t + 1] : 0;
    int s = v0 + v1;
    sbuf[t] = s;
    __syncthreads();
    for (int off = 1; off < 256; off <<= 1) {
        int add = (t >= off) ? sbuf[t - off] : 0;
        __syncthreads();
        sbuf[t] += add;
        __syncthreads();
    }
    int excl = sbuf[t] - s;
    if (2 * t < BN)     { lrs[2 * t] = excl;      cur[2 * t] = excl; }
    if (2 * t + 1 < BN) { lrs[2 * t + 1] = excl + v0; cur[2 * t + 1] = excl + v0; }
    __syncthreads();

    // fill local CSR (random writes stay in LDS)
    for (int i = t; i < cnt; i += 256) {
        u32 p = sedge[i];
        int pos = atomicAdd(&cur[p >> 17], 1);
        lcsr[pos] = (int)(p & 0x1FFFF);
    }
    __syncthreads();

    // coalesced writeout
    for (int i = t; i < cnt; i += 256) csr[base_ + i] = lcsr[i];
    int n0 = b * BN;
    for (int i = t; i < BN; i += 256) {
        int n = n0 + i;
        if (n < N_NODES) {
            int dg = hist[i];
            float dv = rsqrtf((float)dg + 1.0f);
            meta[n] = make_int4(base_ + lrs[i], dg, __float_as_int(dv), 0);
            dinv[n] = dv;
        }
    }
}

// ---------------- GEMM1: h1s = f16((x @ W1) * dinv[row])  [N,64] ----------------
// xs stride 140 floats: float4-aligned, rows spread across banks.

__global__ __launch_bounds__(256) void k_gemm1(const float* __restrict__ x,
                                               const float* __restrict__ W1,
                                               const float* __restrict__ dinv,
                                               u16* __restrict__ h1s) {
    __shared__ float xs[64 * 140];     // 35 KB
    __shared__ float wsh[DIN * DH];    // 32 KB
    int t = threadIdx.x;
    int row0 = blockIdx.x * 64;

    for (int it = 0; it < 8; ++it) {
        int idx = (it * 256 + t) * 4;
        int r = idx >> 7, c = idx & 127;
        float4 v = make_float4(0.f, 0.f, 0.f, 0.f);
        if (row0 + r < N_NODES) v = *(const float4*)&x[(size_t)(row0 + r) * DIN + c];
        *(float4*)&xs[r * 140 + c] = v;
    }
    for (int it = 0; it < 8; ++it) {
        int idx = (it * 256 + t) * 4;
        *(float4*)&wsh[idx] = *(const float4*)&W1[idx];
    }
    __syncthreads();

    int tr = t & 15;   // feature group: features tr*4..tr*4+3
    int tc = t >> 4;   // row group: rows tc*4..tc*4+3
    float acc[4][4] = {};
    for (int kb = 0; kb < DIN; kb += 4) {
        float4 w0 = *(const float4*)&wsh[(kb + 0) * DH + tr * 4];
        float4 w1 = *(const float4*)&wsh[(kb + 1) * DH + tr * 4];
        float4 w2 = *(const float4*)&wsh[(kb + 2) * DH + tr * 4];
        float4 w3 = *(const float4*)&wsh[(kb + 3) * DH + tr * 4];
#pragma unroll
        for (int i = 0; i < 4; ++i) {
            float4 xv = *(const float4*)&xs[(tc * 4 + i) * 140 + kb];
            acc[i][0] += xv.x * w0.x; acc[i][1] += xv.x * w0.y;
            acc[i][2] += xv.x * w0.z; acc[i][3] += xv.x * w0.w;
            acc[i][0] += xv.y * w1.x; acc[i][1] += xv.y * w1.y;
            acc[i][2] += xv.y * w1.z; acc[i][3] += xv.y * w1.w;
            acc[i][0] += xv.z * w2.x; acc[i][1] += xv.z * w2.y;
            acc[i][2] += xv.z * w2.z; acc[i][3] += xv.z * w2.w;
            acc[i][0] += xv.w * w3.x; acc[i][1] += xv.w * w3.y;
            acc[i][2] += xv.w * w3.z; acc[i][3] += xv.w * w3.w;
        }
    }
#pragma unroll
    for (int i = 0; i < 4; ++i) {
        int row = row0 + tc * 4 + i;
        if (row < N_NODES) {
            float dv = dinv[row];
            ushort4 o;
            o.x = __half_as_ushort(__float2half(acc[i][0] * dv));
            o.y = __half_as_ushort(__float2half(acc[i][1] * dv));
            o.z = __half_as_ushort(__float2half(acc[i][2] * dv));
            o.w = __half_as_ushort(__float2half(acc[i][3] * dv));
            *(ushort4*)&h1s[(size_t)row * DH + tr * 4] = o;
        }
    }
}

// ---------------- agg1 (pull): h1 = relu(dinv*(sum h1s[src] + h1s[n]) + b1) ----------------
// one wave per node; lane = (edge-slot es 0..3, feature-pair fp 0..15); 8 B/lane
// gathers, f16 packed accumulation (v_pk_add_f16).

__global__ __launch_bounds__(256) void k_agg1(const u16* __restrict__ h1s,
                                              const int4* __restrict__ meta,
                                              const int* __restrict__ csr,
                                              const float* __restrict__ b1,
                                              float* __restrict__ h1) {
    int node = blockIdx.x * 4 + (threadIdx.x >> 6);
    if (node >= N_NODES) return;
    node = __builtin_amdgcn_readfirstlane(node);
    int lane = threadIdx.x & 63;
    int es = lane >> 4, fp = lane & 15;
    int4 me = meta[node];
    int s0 = me.x, d = me.y;
    float dv = __int_as_float(me.z);
    const uint2* rows = (const uint2*)h1s;  // row stride = 16 uint2
    __half2 A01 = __float2half2_rn(0.f), A23 = __float2half2_rn(0.f);
    if (es == 0) {
        uint2 v = rows[(u32)(node * 16 + fp)];  // self
        A01 = u2h(v.x); A23 = u2h(v.y);
    }
    for (int base = 0; base < d; base += 64) {
        int nn = d - base; if (nn > 64) nn = 64;
        int myidx = (lane < nn) ? csr[s0 + base + lane] : 0;
        int j = 0;
        for (; j + 16 <= nn; j += 16) {
            int x0 = __builtin_amdgcn_ds_bpermute((j + es) * 4, myidx);
            int x1 = __builtin_amdgcn_ds_bpermute((j + 4 + es) * 4, myidx);
            int x2 = __builtin_amdgcn_ds_bpermute((j + 8 + es) * 4, myidx);
            int x3 = __builtin_amdgcn_ds_bpermute((j + 12 + es) * 4, myidx);
            uint2 v0 = rows[(u32)(x0 * 16 + fp)];
            uint2 v1 = rows[(u32)(x1 * 16 + fp)];
            uint2 v2 = rows[(u32)(x2 * 16 + fp)];
            uint2 v3 = rows[(u32)(x3 * 16 + fp)];
            A01 = __hadd2(A01, u2h(v0.x)); A23 = __hadd2(A23, u2h(v0.y));
            A01 = __hadd2(A01, u2h(v1.x)); A23 = __hadd2(A23, u2h(v1.y));
            A01 = __hadd2(A01, u2h(v2.x)); A23 = __hadd2(A23, u2h(v2.y));
            A01 = __hadd2(A01, u2h(v3.x)); A23 = __hadd2(A23, u2h(v3.y));
        }
        for (; j < nn; j += 4) {
            int x = __builtin_amdgcn_ds_bpermute((j + es) * 4, myidx);
            if (j + es < nn) {
                uint2 v = rows[(u32)(x * 16 + fp)];
                A01 = __hadd2(A01, u2h(v.x)); A23 = __hadd2(A23, u2h(v.y));
            }
        }
    }
    // butterfly-reduce across the 4 edge slots (packed adds)
    A01 = __hadd2(A01, u2h((u32)__shfl_xor((int)h2u(A01), 16, 64)));
    A23 = __hadd2(A23, u2h((u32)__shfl_xor((int)h2u(A23), 16, 64)));
    A01 = __hadd2(A01, u2h((u32)__shfl_xor((int)h2u(A01), 32, 64)));
    A23 = __hadd2(A23, u2h((u32)__shfl_xor((int)h2u(A23), 32, 64)));
    if (es == 0) {
        float4 bv = ((const float4*)b1)[fp];
        float4 o;
        o.x = fmaxf(__low2float(A01)  * dv + bv.x, 0.f);
        o.y = fmaxf(__high2float(A01) * dv + bv.y, 0.f);
        o.z = fmaxf(__low2float(A23)  * dv + bv.z, 0.f);
        o.w = fmaxf(__high2float(A23) * dv + bv.w, 0.f);
        ((float4*)h1)[(u32)(node * 16 + fp)] = o;
    }
}

// ---------------- GEMM2: h2s = f16((h1 @ W2) * dinv[row])  [N,64-padded] ----------------

__global__ __launch_bounds__(256) void k_gemm2(const float* __restrict__ h1,
                                               const float* __restrict__ W2,
                                               const float* __restrict__ dinv,
                                               u16* __restrict__ h2s) {
    __shared__ float xs[64 * 68];
    __shared__ float wsh[DH * DOUT];
    int t = threadIdx.x;
    int row0 = blockIdx.x * 64;

    for (int it = 0; it < 4; ++it) {
        int idx = (it * 256 + t) * 4;
        int r = idx >> 6, c = idx & 63;
        float4 v = make_float4(0.f, 0.f, 0.f, 0.f);
        if (row0 + r < N_NODES) v = *(const float4*)&h1[(size_t)(row0 + r) * DH + c];
        *(float4*)&xs[r * 68 + c] = v;
    }
    for (int idx = t * 4; idx < DH * DOUT; idx += 1024) {
        *(float4*)&wsh[idx] = *(const float4*)&W2[idx];
    }
    __syncthreads();

    int fg = t & 7;
    int rg = t >> 3;
    float acc[2][5] = {};
    for (int k = 0; k < DH; ++k) {
        float x0 = xs[(rg * 2 + 0) * 68 + k];
        float x1 = xs[(rg * 2 + 1) * 68 + k];
#pragma unroll
        for (int j = 0; j < 5; ++j) {
            float w = wsh[k * DOUT + fg * 5 + j];
            acc[0][j] += x0 * w;
            acc[1][j] += x1 * w;
        }
    }
#pragma unroll
    for (int i = 0; i < 2; ++i) {
        int row = row0 + rg * 2 + i;
        if (row < N_NODES) {
            float dvv = dinv[row];
#pragma unroll
            for (int j = 0; j < 5; ++j)
                h2s[(size_t)row * 64 + fg * 5 + j] =
                    __half_as_ushort(__float2half(acc[i][j] * dvv));
        }
    }
}

// ---------------- agg2 (pull) + bias + log_softmax ----------------
// same slot structure; only fp<10 (40 features) active on the load side.

__global__ __launch_bounds__(256) void k_agg2(const u16* __restrict__ h2s,
                                              const int4* __restrict__ meta,
                                              const int* __restrict__ csr,
                                              const float* __restrict__ b2,
                                              float* __restrict__ out) {
    int node = blockIdx.x * 4 + (threadIdx.x >> 6);
    if (node >= N_NODES) return;
    node = __builtin_amdgcn_readfirstlane(node);
    int lane = threadIdx.x & 63;
    int es = lane >> 4, fp = lane & 15;
    bool act = fp < 10;
    int4 me = meta[node];
    int s0 = me.x, d = me.y;
    float dv = __int_as_float(me.z);
    const uint2* rows = (const uint2*)h2s;  // padded row stride = 16 uint2
    __half2 A01 = __float2half2_rn(0.f), A23 = __float2half2_rn(0.f);
    if (es == 0 && act) {
        uint2 v = rows[(u32)(node * 16 + fp)];  // self
        A01 = u2h(v.x); A23 = u2h(v.y);
    }
    for (int base = 0; base < d; base += 64) {
        int nn = d - base; if (nn > 64) nn = 64;
        int myidx = (lane < nn) ? csr[s0 + base + lane] : 0;
        int j = 0;
        for (; j + 16 <= nn; j += 16) {
            int x0 = __builtin_amdgcn_ds_bpermute((j + es) * 4, myidx);
            int x1 = __builtin_amdgcn_ds_bpermute((j + 4 + es) * 4, myidx);
            int x2 = __builtin_amdgcn_ds_bpermute((j + 8 + es) * 4, myidx);
            int x3 = __builtin_amdgcn_ds_bpermute((j + 12 + es) * 4, myidx);
            if (act) {
                uint2 v0 = rows[(u32)(x0 * 16 + fp)];
                uint2 v1 = rows[(u32)(x1 * 16 + fp)];
                uint2 v2 = rows[(u32)(x2 * 16 + fp)];
                uint2 v3 = rows[(u32)(x3 * 16 + fp)];
                A01 = __hadd2(A01, u2h(v0.x)); A23 = __hadd2(A23, u2h(v0.y));
                A01 = __hadd2(A01, u2h(v1.x)); A23 = __hadd2(A23, u2h(v1.y));
                A01 = __hadd2(A01, u2h(v2.x)); A23 = __hadd2(A23, u2h(v2.y));
                A01 = __hadd2(A01, u2h(v3.x)); A23 = __hadd2(A23, u2h(v3.y));
            }
        }
        for (; j < nn; j += 4) {
            int x = __builtin_amdgcn_ds_bpermute((j + es) * 4, myidx);
            if (act && j + es < nn) {
                uint2 v = rows[(u32)(x * 16 + fp)];
                A01 = __hadd2(A01, u2h(v.x)); A23 = __hadd2(A23, u2h(v.y));
            }
        }
    }
    // butterfly-reduce across the 4 edge slots
    A01 = __hadd2(A01, u2h((u32)__shfl_xor((int)h2u(A01), 16, 64)));
    A23 = __hadd2(A23, u2h((u32)__shfl_xor((int)h2u(A23), 16, 64)));
    A01 = __hadd2(A01, u2h((u32)__shfl_xor((int)h2u(A01), 32, 64)));
    A23 = __hadd2(A23, u2h((u32)__shfl_xor((int)h2u(A23), 32, 64)));

    // bias + log_softmax over 40 features (10 fp groups x 4)
    float4 bv = act ? ((const float4*)b2)[fp] : make_float4(0.f, 0.f, 0.f, 0.f);
    float v0 = act ? __low2float(A01)  * dv + bv.x : -INFINITY;
    float v1 = act ? __high2float(A01) * dv + bv.y : -INFINITY;
    float v2 = act ? __low2float(A23)  * dv + bv.z : -INFINITY;
    float v3 = act ? __high2float(A23) * dv + bv.w : -INFINITY;
    float m = fmaxf(fmaxf(v0, v1), fmaxf(v2, v3));
    m = fmaxf(m, __shfl_xor(m, 1, 64));
    m = fmaxf(m, __shfl_xor(m, 2, 64));
    m = fmaxf(m, __shfl_xor(m, 4, 64));
    m = fmaxf(m, __shfl_xor(m, 8, 64));
    float ex = act ? (expf(v0 - m) + expf(v1 - m) + expf(v2 - m) + expf(v3 - m)) : 0.f;
    ex += __shfl_xor(ex, 1, 64);
    ex += __shfl_xor(ex, 2, 64);
    ex += __shfl_xor(ex, 4, 64);
    ex += __shfl_xor(ex, 8, 64);
    float lse = m + logf(ex);
    if (es == 0 && act) {
        float4 o = make_float4(v0 - lse, v1 - lse, v2 - lse, v3 - lse);
        *(float4*)&out[(u32)(node * 40 + fp * 4)] = o;
    }
}

// ---------------- launch ----------------

extern "C" void kernel_launch(void* const* d_in, const int* in_sizes, int n_in,
                              void* d_out, int out_size, void* d_ws, size_t ws_size,
                              hipStream_t stream) {
    const float* x  = (const float*)d_in[0];
    const float* W1 = (const float*)d_in[1];
    const float* b1 = (const float*)d_in[2];
    const float* W2 = (const float*)d_in[3];
    const float* b2 = (const float*)d_in[4];
    const int* eidx = (const int*)d_in[5];
    const int* srcp = eidx;
    const int* dstp = eidx + N_EDGES;
    float* out = (float*)d_out;

    char* w = (char*)d_ws;
    int* gcur    = (int*)w;   w += sizeof(int) * NB;
    float* dinv  = (float*)w; w += sizeof(float) * N_NODES + 48;  // keep int4 alignment
    int4* meta   = (int4*)w;  w += sizeof(int4) * N_NODES;
    u32* staged  = (u32*)w;   w += sizeof(u32) * (size_t)NB * CAP;       // 8 MB
    int* csr     = (int*)w;   w += sizeof(int) * N_EDGES;                // 6.4 MB
    u16* h1s     = (u16*)w;   w += sizeof(u16) * (size_t)N_NODES * DH;   // f16 [N,64]
    float* h1    = (float*)w; w += sizeof(float) * (size_t)N_NODES * DH; // f32 [N,64]
    u16* h2s     = h1s;  // alias: h1s dead after agg1; h2s is f16 [N,64-padded]

    hipMemsetAsync(gcur, 0, sizeof(int) * NB, stream);
    k_bin<<<BIN_BLOCKS, 256, 0, stream>>>(srcp, dstp, gcur, staged);
    k_csr<<<NB, 256, 0, stream>>>(gcur, staged, csr, meta, dinv);
    k_gemm1<<<(N_NODES + 63) / 64, 256, 0, stream>>>(x, W1, dinv, h1s);
    k_agg1<<<(N_NODES + 3) / 4, 256, 0, stream>>>(h1s, meta, csr, b1, h1);
    k_gemm2<<<(N_NODES + 63) / 64, 256, 0, stream>>>(h1, W2, dinv, h2s);
    k_agg2<<<(N_NODES + 3) / 4, 256, 0, stream>>>(h2s, meta, csr, b2, out);
}